// Round 12
// baseline (96.589 us; speedup 1.0000x reference)
//
#include <hip/hip_runtime.h>
#include <math.h>

static constexpr int NPT = 98;
static constexpr float CSCALE_HALF = 0.155064240f;  // 0.5 * sqrt(log2(e)/15)

#if __has_builtin(__builtin_amdgcn_exp2f)
#define EXP2F(x) __builtin_amdgcn_exp2f(x)
#else
#define EXP2F(x) exp2f(x)
#endif
#if __has_builtin(__builtin_amdgcn_sqrtf)
#define SQRTF(x) __builtin_amdgcn_sqrtf(x)
#else
#define SQRTF(x) sqrtf(x)
#endif

typedef float v2f __attribute__((ext_vector_type(2)));
typedef float v4a __attribute__((ext_vector_type(4)));               // 16B aligned
typedef float v4fu __attribute__((ext_vector_type(4), aligned(8)));  // 8B aligned
typedef _Float16 h2 __attribute__((ext_vector_type(2)));
typedef _Float16 h4 __attribute__((ext_vector_type(4)));

#if __has_builtin(__builtin_amdgcn_fdot2)
#define FDOT2(a, b, c) __builtin_amdgcn_fdot2((a), (b), (c), false)
#else
#define FDOT2(a, b, c) fmaf((float)(a).x, (float)(b).x, fmaf((float)(a).y, (float)(b).y, (c)))
#endif

#if __has_builtin(__builtin_amdgcn_cvt_pkrtz)
#define PKRTZ(x, y) __builtin_bit_cast(h2, __builtin_amdgcn_cvt_pkrtz((x), (y)))
#else
static __device__ __forceinline__ h2 PKRTZ(float x, float y) {
    h2 r; r.x = (_Float16)x; r.y = (_Float16)y; return r;
}
#endif

// ---- Per-wave LDS slice (h4 slots {cx,cy,tx,ty}, f16, 8B each) ----
// Curves circular: M=2h segments + dup of first DUPN (c0:32, others:6).
//  c0: base   0, M=64, dup[64,96)          c4: base 162, M=14 -> [162,182)
//  c1: base  96, M=16, dup 6 -> [96,118)   c5: base 182, M=14 -> [182,202)
//  c2: base 118, M=16 -> [118,140)         c6: base 202, M=22 -> [202,230)
//  c3: base 140, M=16 -> [140,162)         c7: base 230, M=18 -> [230,254)
// Two-column circulant: lane holds cols {j, j+h}; a read at offset t serves
// class t (vs col j) and class h-t (vs col j+h). U = sum C(t) + 1/2 C(h);
// curve total = diag + 2U.
//
// 4 waves/block, one element/wave, no block barriers in the hot path
// (staging->read deps are wave-internal: s_waitcnt lgkmcnt(0)).
// launch_bounds(256,4): 128-VGPR cap — R10 showed (256,8) strangles the
// allocator to 24 VGPRs -> zero ILP -> 5x stall blowup.
//
// Single dispatch: per-block partial -> ws; last-done block (threadfence +
// atomicAdd counter) sums partials in fixed index order -> bit-deterministic.

__device__ __forceinline__ float wdt(h4 si, h4 sj) {
    h2 dc = si.xy - sj.xy;                         // v_pk_add_f16
    float d2 = FDOT2(dc, dc, 0.0f);                // v_dot2_f32_f16 (pre-scaled)
    float dt = FDOT2(si.zw, sj.zw, 0.0f);
    return EXP2F(-d2) * dt;
}

__global__ __launch_bounds__(256, 4)   // cap 128 VGPR (natural ~60-80): no spill
void lddmm_main(const float* __restrict__ pred, const float* __restrict__ gt,
                float* __restrict__ ws, int* __restrict__ cnt,
                float* __restrict__ out, float invbatch) {
    __shared__ h4 sh[4][256];
    __shared__ float part[4];
    __shared__ float red[256];
    __shared__ int isLast;
    const int tid = threadIdx.x;
    const int wave = tid >> 6;
    const int lane = tid & 63;
    const int b = blockIdx.x * 4 + wave;

    const float* pf = pred + (size_t)b * (2 * NPT);
    const float* gf = gt + (size_t)b * (2 * NPT);
    const v2f* g2 = (const v2f*)gf;
    h4* sw = sh[wave];

    // eye-corner loads issued early (consumed at the very end)
    v2f e0 = g2[60];
    v2f e1 = g2[72];

    float diag = 0.0f;    // class-0: sum |tau|^2 (f32, exact)
    float accS = 0.0f;    // x1 bucket (c0 mirror C(32))
    float accA = 0.0f;    // x2 bucket, chain A
    float accB = 0.0f;    // x2 bucket, chain B
    float dsum = 0.0f;

    // ---- staging: 180 segments in f16 (+ wrap dups), 3 passes, global loads
    #pragma unroll
    for (int pass = 0; pass < 3; ++pass) {
        int s = lane + 64 * pass;
        if (s < 180) {
            int A, NS, B, rel;
            if (s < 64)       { A = 0;  NS = 32; B = 0;   rel = s; }
            else if (s < 80)  { A = 33; NS = 8;  B = 96;  rel = s - 64; }
            else if (s < 96)  { A = 42; NS = 8;  B = 118; rel = s - 80; }
            else if (s < 112) { A = 51; NS = 8;  B = 140; rel = s - 96; }
            else if (s < 126) { A = 60; NS = 7;  B = 162; rel = s - 112; }
            else if (s < 140) { A = 68; NS = 7;  B = 182; rel = s - 126; }
            else if (s < 162) { A = 76; NS = 11; B = 202; rel = s - 140; }
            else              { A = 88; NS = 9;  B = 230; rel = s - 162; }
            bool isg = rel >= NS;
            int a = A + (isg ? rel - NS : rel);
            const float* src = isg ? gf : pf;
            v4fu q = *(const v4fu*)(src + 2 * a);   // {x0,y0,x1,y1}
            v2f c = (q.xy + q.zw) * CSCALE_HALF;
            v2f tau = q.zw - q.xy;
            if (isg) tau = -tau;
            diag = fmaf(tau.x, tau.x, diag);
            diag = fmaf(tau.y, tau.y, diag);
            h2 ch = PKRTZ(c.x, c.y);
            h2 th = PKRTZ(tau.x, tau.y);
            h4 v; v.x = ch.x; v.y = ch.y; v.z = th.x; v.w = th.y;
            sw[B + rel] = v;
            int DUPN = (B == 0) ? 32 : 6;
            if (rel < DUPN) sw[B + 2 * NS + rel] = v;   // circular dup
        }
    }

    // ---- landmark mean distance (f32, one float4 pass: 2 points/lane)
    if (lane < 49) {
        v4a p4 = *(const v4a*)(pf + 4 * lane);
        v4a g4 = *(const v4a*)(gf + 4 * lane);
        v2f d0 = p4.xy - g4.xy;
        v2f d1 = p4.zw - g4.zw;
        dsum = SQRTF(d0.x * d0.x + d0.y * d0.y)
             + SQRTF(d1.x * d1.x + d1.y * d1.y);
    }

    // wave-local LDS fence: this wave's ds_writes complete before its reads.
    asm volatile("s_waitcnt lgkmcnt(0)" ::: "memory");

    // ---- phase A: curve 0 (M=64, h=32), cols {lane, lane+32}
    {
        h4 sjA = sw[lane];
        h4 sjB = sw[lane + 32];
        #pragma unroll 8          // wide ILP: 8 ds_read_b64 in flight
        for (int t = 1; t <= 15; ++t) {
            h4 r = sw[lane + t];
            accA += wdt(r, sjA);
            accB += wdt(r, sjB);
        }
        { h4 r = sw[lane + 16]; accA += wdt(r, sjA); }  // t=16: sjA only
        accS += wdt(sjA, sjB);   // mirror: sum over 64 lanes = C(32) -> x1
    }

    // ---- phase B: curves c1..c7 (58 lanes), cols {jl, jl+h}
    {
        int base, jl, h, TA, TB; float mm;
        if      (lane < 8)  { base = 96;  jl = lane;      h = 8;  TA = 4; TB = 3; mm = 1.f; }
        else if (lane < 16) { base = 118; jl = lane - 8;  h = 8;  TA = 4; TB = 3; mm = 1.f; }
        else if (lane < 24) { base = 140; jl = lane - 16; h = 8;  TA = 4; TB = 3; mm = 1.f; }
        else if (lane < 31) { base = 162; jl = lane - 24; h = 7;  TA = 3; TB = 3; mm = 1.f; }
        else if (lane < 38) { base = 182; jl = lane - 31; h = 7;  TA = 3; TB = 3; mm = 1.f; }
        else if (lane < 49) { base = 202; jl = lane - 38; h = 11; TA = 5; TB = 5; mm = 1.f; }
        else if (lane < 58) { base = 230; jl = lane - 49; h = 9;  TA = 4; TB = 4; mm = 1.f; }
        else                { base = 202; jl = 0;         h = 11; TA = 0; TB = 0; mm = 0.f; }
        const h4* sp = sw + base + jl;
        h4 sjA = sp[0];
        h4 sjB = sp[h];
        accA = fmaf(mm, wdt(sjA, sjB), accA);   // mirror = 1/2 C(h) -> x2
        #pragma unroll
        for (int t = 1; t <= 5; ++t) {
            h4 u1 = sp[t];
            h4 u2 = sp[h + t];
            float mA = (t <= TA) ? 1.0f : 0.0f;
            float mB = (t <= TB) ? 1.0f : 0.0f;
            accA = fmaf(mA, wdt(u1, sjA) + wdt(u2, sjB), accA);  // C(t)
            accB = fmaf(mB, wdt(u1, sjB) + wdt(u2, sjA), accB);  // C(h-t)
        }
    }

    // curve total = diag + accS + 2*(accA+accB); combine with landmark term
    float v = 0.8f * dsum + 0.2f * (fmaf(2.0f, accA + accB, diag + accS));
    #pragma unroll
    for (int off = 32; off >= 1; off >>= 1) v += __shfl_xor(v, off, 64);

    if (lane == 0) {
        v2f de = e0 - e1;
        float eye = SQRTF(de.x * de.x + de.y * de.y);
        part[wave] = v / ((float)NPT * eye);
    }
    __syncthreads();

    // ---- block partial -> ws; last-done block reduces all partials
    if (tid == 0) {
        ws[blockIdx.x] = (part[0] + part[1]) + (part[2] + part[3]);
        __threadfence();                       // release: partial visible device-wide
        int old = atomicAdd(cnt, 1);
        isLast = (old == (int)gridDim.x - 1);
    }
    __syncthreads();
    if (isLast) {                              // block-uniform branch
        __threadfence();                       // acquire all partials
        const float4* w4 = (const float4*)ws;
        const int n4 = (int)gridDim.x / 4;
        float s = 0.0f;
        for (int i = tid; i < n4; i += 256) {
            float4 q = w4[i];
            s += (q.x + q.y) + (q.z + q.w);
        }
        red[tid] = s;
        __syncthreads();
        #pragma unroll
        for (int off = 128; off >= 1; off >>= 1) {
            if (tid < off) red[tid] += red[tid + off];
            __syncthreads();
        }
        if (tid == 0) out[0] = red[0] * invbatch;
    }
}

extern "C" void kernel_launch(void* const* d_in, const int* in_sizes, int n_in,
                              void* d_out, int out_size, void* d_ws, size_t ws_size,
                              hipStream_t stream) {
    const float* pred = (const float*)d_in[0];
    const float* gt = (const float*)d_in[1];
    float* out = (float*)d_out;
    float* ws = (float*)d_ws;
    const int batch = in_sizes[0] / (2 * NPT);
    const int nblk = batch / 4;                       // 4096 blocks, 1 elem/wave

    int* cnt = (int*)((char*)d_ws + (size_t)nblk * sizeof(float));
    hipMemsetAsync(cnt, 0, sizeof(int), stream);      // graph-capturable
    lddmm_main<<<nblk, 256, 0, stream>>>(pred, gt, ws, cnt, out,
                                         1.0f / (float)batch);
}

// Round 13
// 26.517 us; speedup vs baseline: 3.6426x; 3.6426x over previous
//
#include <hip/hip_runtime.h>
#include <math.h>

static constexpr int NPT = 98;
static constexpr float CSCALE_HALF = 0.155064240f;  // 0.5 * sqrt(log2(e)/15)

#if __has_builtin(__builtin_amdgcn_exp2f)
#define EXP2F(x) __builtin_amdgcn_exp2f(x)
#else
#define EXP2F(x) exp2f(x)
#endif
#if __has_builtin(__builtin_amdgcn_sqrtf)
#define SQRTF(x) __builtin_amdgcn_sqrtf(x)
#else
#define SQRTF(x) sqrtf(x)
#endif

typedef float v2f __attribute__((ext_vector_type(2)));
typedef float v4a __attribute__((ext_vector_type(4)));               // 16B aligned
typedef float v4fu __attribute__((ext_vector_type(4), aligned(8)));  // 8B aligned
typedef _Float16 h2 __attribute__((ext_vector_type(2)));
typedef _Float16 h4 __attribute__((ext_vector_type(4)));

#if __has_builtin(__builtin_amdgcn_fdot2)
#define FDOT2(a, b, c) __builtin_amdgcn_fdot2((a), (b), (c), false)
#else
#define FDOT2(a, b, c) fmaf((float)(a).x, (float)(b).x, fmaf((float)(a).y, (float)(b).y, (c)))
#endif

#if __has_builtin(__builtin_amdgcn_cvt_pkrtz)
#define PKRTZ(x, y) __builtin_bit_cast(h2, __builtin_amdgcn_cvt_pkrtz((x), (y)))
#else
static __device__ __forceinline__ h2 PKRTZ(float x, float y) {
    h2 r; r.x = (_Float16)x; r.y = (_Float16)y; return r;
}
#endif

// ---- Per-wave LDS slice (h4 slots {cx,cy,tx,ty}, f16, 8B each) ----
// Curves circular: M=2h segments + dup of first DUPN (c0:32, others:6).
//  c0: base   0, M=64, dup[64,96)          c4: base 162, M=14 -> [162,182)
//  c1: base  96, M=16, dup 6 -> [96,118)   c5: base 182, M=14 -> [182,202)
//  c2: base 118, M=16 -> [118,140)         c6: base 202, M=22 -> [202,230)
//  c3: base 140, M=16 -> [140,162)         c7: base 230, M=18 -> [230,254)
// Slots 254/255: scratch. Two-column circulant: lane holds cols {j, j+h};
// a read at offset t serves class t (vs col j) and class h-t (vs col j+h).
// U = sum C(t) + 1/2 C(h); curve total = diag + 2U.
//
// R13: per-lane static tables (staging curve map, phase-B lane map) moved
// from ~30-VALU select chains to compile-time __constant__ u32 LUTs.
// Two-kernel structure kept: R10/R12 showed the fused atomic/fence epilogue
// reproducibly poisons codegen to 24 VGPR / 4x stall blowup.

// Staging LUT: a[6:0] point idx | isg bit7 | dst[15:8] | dup[23:16] (255=none)
struct SLut { unsigned v[192]; };
static constexpr SLut make_slut() {
    SLut L{};
    constexpr int A[8]  = {0, 33, 42, 51, 60, 68, 76, 88};
    constexpr int NS[8] = {32, 8, 8, 8, 7, 7, 11, 9};
    constexpr int BB[8] = {0, 96, 118, 140, 162, 182, 202, 230};
    int s = 0;
    for (int c = 0; c < 8; ++c) {
        int dupn = (c == 0) ? 32 : 6;
        for (int rel = 0; rel < 2 * NS[c]; ++rel, ++s) {
            bool isg = rel >= NS[c];
            int a = A[c] + (isg ? rel - NS[c] : rel);
            int dst = BB[c] + rel;
            int dup = (rel < dupn) ? (BB[c] + 2 * NS[c] + rel) : 255;
            L.v[s] = (unsigned)a | (isg ? 0x80u : 0u)
                   | ((unsigned)dst << 8) | ((unsigned)dup << 16);
        }
    }
    for (; s < 192; ++s) L.v[s] = 0u | (254u << 8) | (255u << 16);
    return L;
}
__constant__ SLut cSLUT = make_slut();

// Phase-B LUT: spOff[7:0] | h[11:8] | TA[14:12] | TB[17:15] | mm bit18
struct BLut { unsigned v[64]; };
static constexpr BLut make_blut() {
    BLut L{};
    // lane ranges: [0,8)c1 [8,16)c2 [16,24)c3 [24,31)c4 [31,38)c5
    //              [38,49)c6 [49,58)c7 [58,64) idle
    constexpr int lo[8]   = {0, 8, 16, 24, 31, 38, 49, 58};
    constexpr int bs[8]   = {96, 118, 140, 162, 182, 202, 230, 202};
    constexpr int hh[8]   = {8, 8, 8, 7, 7, 11, 9, 11};
    constexpr int ta[8]   = {4, 4, 4, 3, 3, 5, 4, 0};
    constexpr int tb[8]   = {3, 3, 3, 3, 3, 5, 4, 0};
    constexpr int mmv[8]  = {1, 1, 1, 1, 1, 1, 1, 0};
    for (int g = 0; g < 8; ++g) {
        int hi = (g < 7) ? lo[g + 1] : 64;
        for (int l = lo[g]; l < hi; ++l) {
            int off = bs[g] + ((g < 7) ? (l - lo[g]) : 0);
            L.v[l] = (unsigned)off | ((unsigned)hh[g] << 8)
                   | ((unsigned)ta[g] << 12) | ((unsigned)tb[g] << 15)
                   | ((unsigned)mmv[g] << 18);
        }
    }
    return L;
}
__constant__ BLut cBLUT = make_blut();

__device__ __forceinline__ float wdt(h4 si, h4 sj) {
    h2 dc = si.xy - sj.xy;                         // v_pk_add_f16
    float d2 = FDOT2(dc, dc, 0.0f);                // v_dot2_f32_f16 (pre-scaled)
    float dt = FDOT2(si.zw, sj.zw, 0.0f);
    return EXP2F(-d2) * dt;
}

__global__ __launch_bounds__(256, 4)   // cap 128 VGPR: no spill, room for ILP
void lddmm_main(const float* __restrict__ pred, const float* __restrict__ gt,
                float* __restrict__ ws) {
    __shared__ h4 sh[4][256];
    const int wave = threadIdx.x >> 6;
    const int lane = threadIdx.x & 63;
    __builtin_assume(lane < 64);
    const int b = blockIdx.x * 4 + wave;

    const float* pf = pred + (size_t)b * (2 * NPT);
    const float* gf = gt + (size_t)b * (2 * NPT);
    const v2f* g2 = (const v2f*)gf;
    h4* sw = sh[wave];

    // eye-corner loads issued early (consumed at the very end)
    v2f e0 = g2[60];
    v2f e1 = g2[72];

    float diag = 0.0f;    // class-0: sum |tau|^2 (f32, exact)
    float accS = 0.0f;    // x1 bucket (c0 mirror C(32))
    float accA = 0.0f;    // x2 bucket, chain A
    float accB = 0.0f;    // x2 bucket, chain B
    float dsum = 0.0f;

    // ---- staging: 180 segments in f16 (+ wrap dups), 3 LUT-driven passes
    #pragma unroll
    for (int pass = 0; pass < 3; ++pass) {
        int s = lane + 64 * pass;
        if (s < 180) {    // folds away for pass 0/1 (s < 128 provably)
            unsigned e = cSLUT.v[s];
            int a = e & 0x7f;
            bool isg = (e & 0x80u) != 0;
            int dst = (int)((e >> 8) & 0xffu);
            int dup = (int)((e >> 16) & 0xffu);
            const float* src = isg ? gf : pf;
            v4fu q = *(const v4fu*)(src + 2 * a);   // {x0,y0,x1,y1}
            v2f c = (q.xy + q.zw) * CSCALE_HALF;
            v2f tau = q.zw - q.xy;
            if (isg) tau = -tau;
            diag = fmaf(tau.x, tau.x, diag);
            diag = fmaf(tau.y, tau.y, diag);
            h2 ch = PKRTZ(c.x, c.y);
            h2 th = PKRTZ(tau.x, tau.y);
            h4 v; v.x = ch.x; v.y = ch.y; v.z = th.x; v.w = th.y;
            sw[dst] = v;
            if (dup != 255) sw[dup] = v;            // circular dup
        }
    }

    // ---- landmark mean distance (f32, one float4 pass: 2 points/lane)
    if (lane < 49) {
        v4a p4 = *(const v4a*)(pf + 4 * lane);
        v4a g4 = *(const v4a*)(gf + 4 * lane);
        v2f d0 = p4.xy - g4.xy;
        v2f d1 = p4.zw - g4.zw;
        dsum = SQRTF(d0.x * d0.x + d0.y * d0.y)
             + SQRTF(d1.x * d1.x + d1.y * d1.y);
    }

    // wave-local LDS fence: this wave's ds_writes complete before its reads.
    asm volatile("s_waitcnt lgkmcnt(0)" ::: "memory");

    // ---- phase A: curve 0 (M=64, h=32), cols {lane, lane+32}
    {
        h4 sjA = sw[lane];
        h4 sjB = sw[lane + 32];
        #pragma unroll 8          // wide ILP: 8 ds_read_b64 in flight
        for (int t = 1; t <= 15; ++t) {
            h4 r = sw[lane + t];
            accA += wdt(r, sjA);
            accB += wdt(r, sjB);
        }
        { h4 r = sw[lane + 16]; accA += wdt(r, sjA); }  // t=16: sjA only
        accS += wdt(sjA, sjB);   // mirror: sum over 64 lanes = C(32) -> x1
    }

    // ---- phase B: curves c1..c7 (58 lanes), LUT-driven cols {jl, jl+h}
    {
        unsigned e = cBLUT.v[lane];
        const h4* sp = sw + (e & 0xffu);
        int h = (int)((e >> 8) & 0xfu);
        int TA = (int)((e >> 12) & 7u);
        int TB = (int)((e >> 15) & 7u);
        float mm = (e & (1u << 18)) ? 1.0f : 0.0f;
        h4 sjA = sp[0];
        h4 sjB = sp[h];
        accA = fmaf(mm, wdt(sjA, sjB), accA);   // mirror = 1/2 C(h) -> x2
        #pragma unroll
        for (int t = 1; t <= 5; ++t) {
            h4 u1 = sp[t];
            h4 u2 = sp[h + t];
            float mA = (t <= TA) ? 1.0f : 0.0f;
            float mB = (t <= TB) ? 1.0f : 0.0f;
            accA = fmaf(mA, wdt(u1, sjA) + wdt(u2, sjB), accA);  // C(t)
            accB = fmaf(mB, wdt(u1, sjB) + wdt(u2, sjA), accB);  // C(h-t)
        }
    }

    // curve total = diag + accS + 2*(accA+accB); combine with landmark term
    float v = 0.8f * dsum + 0.2f * (fmaf(2.0f, accA + accB, diag + accS));
    #pragma unroll
    for (int off = 32; off >= 1; off >>= 1) v += __shfl_xor(v, off, 64);

    if (lane == 0) {
        v2f de = e0 - e1;
        float eye = SQRTF(de.x * de.x + de.y * de.y);
        ws[b] = v / ((float)NPT * eye);
    }
}

__global__ __launch_bounds__(1024)
void lddmm_reduce(const float* __restrict__ ws, float* __restrict__ out,
                  int n4, float invbatch) {
    __shared__ float sm[1024];
    const int t = threadIdx.x;
    const float4* w4 = (const float4*)ws;
    float s = 0.0f;
    for (int i = t; i < n4; i += 1024) {
        float4 v = w4[i];
        s += (v.x + v.y) + (v.z + v.w);
    }
    sm[t] = s;
    __syncthreads();
    for (int off = 512; off >= 1; off >>= 1) {
        if (t < off) sm[t] += sm[t + off];
        __syncthreads();
    }
    if (t == 0) out[0] = sm[0] * invbatch;
}

extern "C" void kernel_launch(void* const* d_in, const int* in_sizes, int n_in,
                              void* d_out, int out_size, void* d_ws, size_t ws_size,
                              hipStream_t stream) {
    const float* pred = (const float*)d_in[0];
    const float* gt = (const float*)d_in[1];
    float* out = (float*)d_out;
    float* ws = (float*)d_ws;
    const int batch = in_sizes[0] / (2 * NPT);

    lddmm_main<<<batch / 4, 256, 0, stream>>>(pred, gt, ws);
    lddmm_reduce<<<1, 1024, 0, stream>>>(ws, out, batch / 4, 1.0f / (float)batch);
}